// Round 2
// baseline (1043.453 us; speedup 1.0000x reference)
//
#include <hip/hip_runtime.h>

// Volume dims (fixed by the reference): frames[T=3][Z=72][Y=512][X=1024], fp32.
#define TT 3
#define ZZ 72
#define YY 512
#define XX 1024
#define FRAME_STRIDE ((long)ZZ * YY * XX)   // 37,748,736 elements
#define ZSTRIDE      ((long)YY * XX)        // 524,288
#define YSTRIDE      ((long)XX)             // 1,024

__device__ __forceinline__ float trilerp_frame(
    const float* __restrict__ fr,   // base of frame t
    long oz0y0, long oz0y1, long oz1y0, long oz1y1,
    int x0, int x1, float wz, float wy, float wx)
{
    float c000 = fr[oz0y0 + x0];
    float c001 = fr[oz0y0 + x1];
    float c010 = fr[oz0y1 + x0];
    float c011 = fr[oz0y1 + x1];
    float c100 = fr[oz1y0 + x0];
    float c101 = fr[oz1y0 + x1];
    float c110 = fr[oz1y1 + x0];
    float c111 = fr[oz1y1 + x1];
    float iwx = 1.0f - wx;
    float c00 = c000 * iwx + c001 * wx;
    float c01 = c010 * iwx + c011 * wx;
    float c10 = c100 * iwx + c101 * wx;
    float c11 = c110 * iwx + c111 * wx;
    float iwy = 1.0f - wy;
    float c0 = c00 * iwy + c01 * wy;
    float c1 = c10 * iwy + c11 * wy;
    return c0 * (1.0f - wz) + c1 * wz;
}

__global__ __launch_bounds__(256) void ZapBenchVolume_kernel(
    const float4* __restrict__ coords,  // (N,4): [z_norm, y_norm, x_norm, t_norm]
    const float*  __restrict__ frames,
    float*        __restrict__ out,
    int n)
{
    int i = blockIdx.x * blockDim.x + threadIdx.x;
    if (i >= n) return;

    float4 c = coords[i];

    // temporal: t0 = clip(floor(t_norm*3), 0, T-1); t1 = min(t0+1, T-1)
    float t_abs = c.w * 3.0f;
    int t0 = (int)floorf(t_abs);
    t0 = min(max(t0, 0), TT - 1);                // [0, 2]  (R0 bug: was clipped to 1)
    float w = t_abs - (float)t0;
    int t1 = min(t0 + 1, TT - 1);

    // spatial: coords[:, :3] * [Z-1, Y-1, X-1]
    float sz = c.x * (float)(ZZ - 1);
    float sy = c.y * (float)(YY - 1);
    float sx = c.z * (float)(XX - 1);
    int z0 = (int)sz;                            // trunc == floor (inputs >= 0)
    int y0 = (int)sy;
    int x0 = (int)sx;
    float wz = sz - (float)z0;                   // weights from UNclamped idx (ref semantics)
    float wy = sy - (float)y0;
    float wx = sx - (float)x0;
    z0 = min(max(z0, 0), ZZ - 1);
    y0 = min(max(y0, 0), YY - 1);
    x0 = min(max(x0, 0), XX - 1);
    int z1 = min(z0 + 1, ZZ - 1);
    int y1 = min(y0 + 1, YY - 1);
    int x1 = min(x0 + 1, XX - 1);

    long oz0y0 = (long)z0 * ZSTRIDE + (long)y0 * YSTRIDE;
    long oz0y1 = (long)z0 * ZSTRIDE + (long)y1 * YSTRIDE;
    long oz1y0 = (long)z1 * ZSTRIDE + (long)y0 * YSTRIDE;
    long oz1y1 = (long)z1 * ZSTRIDE + (long)y1 * YSTRIDE;

    const float* f0 = frames + (long)t0 * FRAME_STRIDE;
    float v0 = trilerp_frame(f0, oz0y0, oz0y1, oz1y0, oz1y1, x0, x1, wz, wy, wx);

    float v1;
    if (t1 != t0) {
        const float* f1 = frames + (long)t1 * FRAME_STRIDE;
        v1 = trilerp_frame(f1, oz0y0, oz0y1, oz1y0, oz1y1, x0, x1, wz, wy, wx);
    } else {
        v1 = v0;   // t_abs in [2,3): both samples identical — skip 8 gathers
    }

    out[i] = v0 * (1.0f - w) + v1 * w;
}

extern "C" void kernel_launch(void* const* d_in, const int* in_sizes, int n_in,
                              void* d_out, int out_size, void* d_ws, size_t ws_size,
                              hipStream_t stream) {
    const float4* coords = (const float4*)d_in[0];   // N*4 floats
    const float*  frames = (const float*)d_in[1];    // T*Z*Y*X floats
    float* out = (float*)d_out;                      // N floats
    int n = in_sizes[0] / 4;

    int block = 256;
    int grid = (n + block - 1) / block;
    ZapBenchVolume_kernel<<<grid, block, 0, stream>>>(coords, frames, out, n);
}